// Round 8
// baseline (455.462 us; speedup 1.0000x reference)
//
#include <hip/hip_runtime.h>
#include <hip/hip_bf16.h>
#include <hip/hip_cooperative_groups.h>
#include <math.h>

namespace cg = cooperative_groups;

#define NN 100000
#define NE 625000
#define DIN 128
#define NROWS 100096                      // 782 tiles * 128 rows
#define NTILES 782

#define SCAN_BS 1024
#define NB 98                             // ceil(NN/1024)

#define HS_STRIDE 264                     // bf16; 528 B rows: 16B-aligned, bank-skewed

typedef __attribute__((ext_vector_type(8))) short bf16x8;
typedef __attribute__((ext_vector_type(4))) float f32x4;

__device__ __forceinline__ unsigned short f2bf(float f) {
    unsigned u = __builtin_bit_cast(unsigned, f);
    u += 0x7fffu + ((u >> 16) & 1u);      // RNE
    return (unsigned short)(u >> 16);
}
__device__ __forceinline__ float bflo(unsigned u) {
    return __builtin_bit_cast(float, u << 16);
}
__device__ __forceinline__ float bfhi(unsigned u) {
    return __builtin_bit_cast(float, u & 0xffff0000u);
}

// ---------------------------------------------------------------------------
// ONE cooperative kernel: prep -> hist -> scan -> fill -> fused gather+GEMM.
// 512 thr (8 waves), LDS 76288 B -> 2 blocks/CU; __launch_bounds__(512,4)
// caps VGPR at 128 (R6's gemm needed 108 -> no spill) -> 4 waves/SIMD.
// ---------------------------------------------------------------------------
__global__ __launch_bounds__(512, 4)
void sage_all(const float* __restrict__ x, const int* __restrict__ ei,
              const float* __restrict__ w_l, const float* __restrict__ b_l,
              const float* __restrict__ w_r,
              const float* __restrict__ w_p, const float* __restrict__ b_p,
              const float* __restrict__ w_s, const float* __restrict__ b_s,
              unsigned short* __restrict__ A, unsigned short* __restrict__ Bp,
              unsigned short* __restrict__ whp, float* __restrict__ bhc,
              int* __restrict__ deg, int* __restrict__ cursor,
              int* __restrict__ bsums, int* __restrict__ elist,
              float* __restrict__ out) {
    cg::grid_group grid = cg::this_grid();
    __shared__ __align__(16) unsigned char smem[76288];

    const int t = threadIdx.x;
    const int G = gridDim.x * 512;
    const int g = blockIdx.x * 512 + t;

    // ===== P0: zero deg | xcast | pack_w (ct-half-contiguous) | pack_heads =====
    for (int i = g; i < NN; i += G) deg[i] = 0;
    for (int i = g; i < NN * 32; i += G) {
        const int n = i >> 5, j4 = (i & 31) * 4;
        float4 v = *reinterpret_cast<const float4*>(x + (size_t)n * DIN + j4);
        ushort4 o = { f2bf(v.x), f2bf(v.y), f2bf(v.z), f2bf(v.w) };
        *reinterpret_cast<ushort4*>(A + (size_t)n * 256 + 128 + j4) = o;
    }
    if (g < 8192) {
        // Bp[(((h*8+kt)*8+c8)*64+L)*8+j] = bf16(w_cat[kt*32+(L>>4)*8+j][(h*8+c8)*16+(L&15)])
        const int h = g >> 12, kt = (g >> 9) & 7, c8 = (g >> 6) & 7, L = g & 63;
        const int k0 = kt * 32 + (L >> 4) * 8;
        const int c = (h * 8 + c8) * 16 + (L & 15);
        unsigned short v[8];
#pragma unroll
        for (int j = 0; j < 8; ++j) {
            const int k = k0 + j;
            const float w = (k < 128) ? w_l[k * 256 + c] : w_r[(k - 128) * 256 + c];
            v[j] = f2bf(w);
        }
        *reinterpret_cast<bf16x8*>(Bp + (size_t)g * 8) =
            *reinterpret_cast<const bf16x8*>(v);
    } else if (g < 8704) {
        const int tid = g - 8192;                 // 0..511
        const int kt = tid >> 6, L = tid & 63;
        const int k0 = kt * 32 + (L >> 4) * 8;
        const int c = L & 15;
        unsigned short v[8];
#pragma unroll
        for (int j = 0; j < 8; ++j) {
            const int k = k0 + j;
            const float w = (c < 7) ? w_p[k * 7 + c] : (c < 13 ? w_s[k * 6 + (c - 7)] : 0.f);
            v[j] = f2bf(w);
        }
        *reinterpret_cast<bf16x8*>(whp + (size_t)tid * 8) =
            *reinterpret_cast<const bf16x8*>(v);
        if (tid < 16)
            bhc[tid] = (tid < 7) ? b_p[tid] : (tid < 13 ? b_s[tid - 7] : 0.f);
    }
    grid.sync();

    // ===== P1: degree histogram =====
    for (int e = g; e < NE; e += G) atomicAdd(&deg[ei[NE + e]], 1);
    grid.sync();

    // ===== P2: scan1 (blocks 0..97, t<256; syncs unguarded) =====
    {
        int* ss = (int*)smem;
        const bool act = (blockIdx.x < NB) && (t < 256);
        int v0 = 0, v1 = 0, v2 = 0, v3 = 0, tsum = 0, base = 0;
        if (act) {
            base = blockIdx.x * SCAN_BS + t * 4;
            if (base + 0 < NN) v0 = deg[base + 0];
            if (base + 1 < NN) v1 = deg[base + 1];
            if (base + 2 < NN) v2 = deg[base + 2];
            if (base + 3 < NN) v3 = deg[base + 3];
            tsum = v0 + v1 + v2 + v3;
            ss[t] = tsum;
        }
        __syncthreads();
        for (int o = 1; o < 256; o <<= 1) {
            int u = 0;
            if (act && t >= o) u = ss[t - o];
            __syncthreads();
            if (act) ss[t] += u;
            __syncthreads();
        }
        if (act) {
            int run = ss[t] - tsum;
            if (base + 0 < NN) cursor[base + 0] = run; run += v0;
            if (base + 1 < NN) cursor[base + 1] = run; run += v1;
            if (base + 2 < NN) cursor[base + 2] = run; run += v2;
            if (base + 3 < NN) cursor[base + 3] = run;
            if (t == 255) bsums[blockIdx.x] = ss[255];
        }
    }
    grid.sync();

    // ===== P3: scan2 (block 0, t<128) =====
    {
        int* ss = (int*)smem;
        const bool act = (blockIdx.x == 0) && (t < 128);
        int v = 0;
        if (act) { v = (t < NB) ? bsums[t] : 0; ss[t] = v; }
        __syncthreads();
        for (int o = 1; o < 128; o <<= 1) {
            int u = 0;
            if (act && t >= o) u = ss[t - o];
            __syncthreads();
            if (act) ss[t] += u;
            __syncthreads();
        }
        if (act && t < NB) bsums[t] = ss[t] - v;
    }
    grid.sync();

    // ===== P4: CSR fill =====
    for (int e = g; e < NE; e += G) {
        const int dst = ei[NE + e];
        const int p = bsums[dst >> 10] + atomicAdd(&cursor[dst], 1);
        elist[p] = ei[e];
    }
    grid.sync();

    // ===== P5: fused gather-mean + GEMM + heads + log_softmax =====
    unsigned short* Bs = (unsigned short*)smem;       // 64 KB B ct-half
    unsigned short* hs = (unsigned short*)smem;       // [128][264] bf16 (alias)
    float* o13 = (float*)(smem + 67584);              // [128][17]

    const int wave = t >> 6;
    const int L = t & 63;
    const int q = L >> 4;
    const int m15 = L & 15;

    for (int tile = blockIdx.x; tile < NTILES; tile += gridDim.x) {
        const int node0 = tile * 128;
        const int n = node0 + wave * 16 + m15;   // this lane's A-frag row

        // stage B half0 (cols 0..127): 64 KB = 8 rounds x 512 thr x 16 B
        {
            const uint4* gsrc = reinterpret_cast<const uint4*>(Bp);
            uint4* ldst = reinterpret_cast<uint4*>(Bs);
#pragma unroll
            for (int r = 0; r < 8; ++r)
                ldst[r * 512 + t] = gsrc[r * 512 + t];
        }

        // gather-mean -> afrag[0..3] (this lane's 32 dims of row n)
        bf16x8 afrag[8];
        {
            float macc[32];
#pragma unroll
            for (int j = 0; j < 32; ++j) macc[j] = 0.f;
            int d = 0, start = 0;
            if (n < NN) {
                d = deg[n];
                start = bsums[n >> 10] + cursor[n] - d;  // cursor = local_pfx + deg
            }
            int srcN = (d > 0) ? elist[start] : 0;
            for (int i = 0; i < d; ++i) {
                const int src = srcN;
                if (i + 1 < d) srcN = elist[start + i + 1];
                const unsigned short* xr = A + (size_t)src * 256 + 128 + q * 8;
                const uint4 v0 = *reinterpret_cast<const uint4*>(xr);
                const uint4 v1 = *reinterpret_cast<const uint4*>(xr + 32);
                const uint4 v2 = *reinterpret_cast<const uint4*>(xr + 64);
                const uint4 v3 = *reinterpret_cast<const uint4*>(xr + 96);
                macc[0]  += bflo(v0.x); macc[1]  += bfhi(v0.x);
                macc[2]  += bflo(v0.y); macc[3]  += bfhi(v0.y);
                macc[4]  += bflo(v0.z); macc[5]  += bfhi(v0.z);
                macc[6]  += bflo(v0.w); macc[7]  += bfhi(v0.w);
                macc[8]  += bflo(v1.x); macc[9]  += bfhi(v1.x);
                macc[10] += bflo(v1.y); macc[11] += bfhi(v1.y);
                macc[12] += bflo(v1.z); macc[13] += bfhi(v1.z);
                macc[14] += bflo(v1.w); macc[15] += bfhi(v1.w);
                macc[16] += bflo(v2.x); macc[17] += bfhi(v2.x);
                macc[18] += bflo(v2.y); macc[19] += bfhi(v2.y);
                macc[20] += bflo(v2.z); macc[21] += bfhi(v2.z);
                macc[22] += bflo(v2.w); macc[23] += bfhi(v2.w);
                macc[24] += bflo(v3.x); macc[25] += bfhi(v3.x);
                macc[26] += bflo(v3.y); macc[27] += bfhi(v3.y);
                macc[28] += bflo(v3.z); macc[29] += bfhi(v3.z);
                macc[30] += bflo(v3.w); macc[31] += bfhi(v3.w);
            }
            const float invd = (d > 0) ? 1.f / (float)d : 0.f;
#pragma unroll
            for (int kt = 0; kt < 4; ++kt) {
                unsigned short vv[8];
#pragma unroll
                for (int j = 0; j < 8; ++j) vv[j] = f2bf(macc[kt * 8 + j] * invd);
                afrag[kt] = *reinterpret_cast<const bf16x8*>(vv);
            }
        }
        // x-half frags (kt 4..7): own row
        {
            const unsigned short* arow = A + (size_t)n * 256;
#pragma unroll
            for (int kt = 4; kt < 8; ++kt)
                afrag[kt] = *reinterpret_cast<const bf16x8*>(arow + kt * 32 + q * 8);
        }

        f32x4 acc[16];
#pragma unroll
        for (int ct = 0; ct < 16; ++ct) acc[ct] = (f32x4){0.f, 0.f, 0.f, 0.f};

        __syncthreads();   // B half0 staged

#pragma unroll
        for (int kt = 0; kt < 8; ++kt)
#pragma unroll
            for (int c8 = 0; c8 < 8; ++c8) {
                bf16x8 b = *reinterpret_cast<const bf16x8*>(
                    Bs + ((size_t)(kt * 8 + c8) * 64 + L) * 8);
                acc[c8] = __builtin_amdgcn_mfma_f32_16x16x32_bf16(afrag[kt], b, acc[c8], 0, 0, 0);
            }
        __syncthreads();   // done reading half0

        // stage B half1 (cols 128..255)
        {
            const uint4* gsrc = reinterpret_cast<const uint4*>(Bp) + 4096;
            uint4* ldst = reinterpret_cast<uint4*>(Bs);
#pragma unroll
            for (int r = 0; r < 8; ++r)
                ldst[r * 512 + t] = gsrc[r * 512 + t];
        }
        __syncthreads();

#pragma unroll
        for (int kt = 0; kt < 8; ++kt)
#pragma unroll
            for (int c8 = 0; c8 < 8; ++c8) {
                bf16x8 b = *reinterpret_cast<const bf16x8*>(
                    Bs + ((size_t)(kt * 8 + c8) * 64 + L) * 8);
                acc[8 + c8] = __builtin_amdgcn_mfma_f32_16x16x32_bf16(afrag[kt], b, acc[8 + c8], 0, 0, 0);
            }
        __syncthreads();   // done reading half1; reuse region as hs

        // epilogue: bias + relu -> hs bf16 (stride 264)
#pragma unroll
        for (int ct = 0; ct < 16; ++ct) {
            const int c = ct * 16 + m15;
            const float blv = b_l[c];
            const int r0 = wave * 16 + q * 4;
#pragma unroll
            for (int r = 0; r < 4; ++r)
                hs[(r0 + r) * HS_STRIDE + c] = f2bf(fmaxf(acc[ct][r] + blv, 0.f));
        }
        __syncthreads();

        // heads via MFMA: wave's 16 rows x 16 (13 used) cols, K=256
        {
            f32x4 acch = (f32x4){0.f, 0.f, 0.f, 0.f};
            const unsigned short* hrow = hs + (size_t)(wave * 16 + m15) * HS_STRIDE;
#pragma unroll
            for (int kt = 0; kt < 8; ++kt) {
                bf16x8 ah = *reinterpret_cast<const bf16x8*>(hrow + kt * 32 + q * 8);
                bf16x8 bh = *reinterpret_cast<const bf16x8*>(whp + ((size_t)(kt * 64 + L)) * 8);
                acch = __builtin_amdgcn_mfma_f32_16x16x32_bf16(ah, bh, acch, 0, 0, 0);
            }
            if (m15 < 13) {
                const float bh = bhc[m15];
#pragma unroll
                for (int r = 0; r < 4; ++r)
                    o13[(wave * 16 + q * 4 + r) * 17 + m15] = acch[r] + bh;
            }
        }
        __syncthreads();

        // log_softmax + write
        if (t < 128) {
            const int gnode = node0 + t;
            if (gnode < NN) {
                float v[7], mx = -1e30f;
#pragma unroll
                for (int j = 0; j < 7; ++j) { v[j] = o13[t * 17 + j]; mx = fmaxf(mx, v[j]); }
                float sum = 0.f;
#pragma unroll
                for (int j = 0; j < 7; ++j) sum += expf(v[j] - mx);
                const float lse = mx + logf(sum);
#pragma unroll
                for (int j = 0; j < 7; ++j) out[(size_t)gnode * 7 + j] = v[j] - lse;

                float u[6], mx2 = -1e30f;
#pragma unroll
                for (int j = 0; j < 6; ++j) { u[j] = o13[t * 17 + 7 + j]; mx2 = fmaxf(mx2, u[j]); }
                float sum2 = 0.f;
#pragma unroll
                for (int j = 0; j < 6; ++j) sum2 += expf(u[j] - mx2);
                const float lse2 = mx2 + logf(sum2);
#pragma unroll
                for (int j = 0; j < 6; ++j) out[(size_t)NN * 7 + (size_t)gnode * 6 + j] = u[j] - lse2;
            }
        }
        __syncthreads();   // protect o13/hs before next tile
    }
}

extern "C" void kernel_launch(void* const* d_in, const int* in_sizes, int n_in,
                              void* d_out, int out_size, void* d_ws, size_t ws_size,
                              hipStream_t stream) {
    const float* x   = (const float*)d_in[0];
    const int*   ei  = (const int*)d_in[1];
    const float* w_l = (const float*)d_in[2];
    const float* b_l = (const float*)d_in[3];
    const float* w_r = (const float*)d_in[4];
    const float* w_p = (const float*)d_in[5];
    const float* b_p = (const float*)d_in[6];
    const float* w_s = (const float*)d_in[7];
    const float* b_s = (const float*)d_in[8];
    float* out = (float*)d_out;

    // workspace layout (~54.7 MB)
    unsigned short* A   = (unsigned short*)d_ws;     // [NROWS][256] bf16: [mean|x]
    unsigned short* Bp  = A + (size_t)NROWS * 256;   // 65536 bf16 (half-contiguous)
    unsigned short* whp = Bp + 65536;                // 4096 bf16 head B-frags
    float* bhc  = (float*)(whp + 4096);              // [16] head biases
    int* deg    = (int*)(bhc + 16);                  // NN
    int* cursor = deg + NN;                          // NN (local prefix)
    int* bsums  = cursor + NN;                       // 128
    int* elist  = bsums + 128;                       // NE

    int nb = 0;
    hipOccupancyMaxActiveBlocksPerMultiprocessor(&nb, sage_all, 512, 0);
    if (nb < 1) nb = 1;
    int gridsz = nb * 256;
    if (gridsz > 512) gridsz = 512;

    void* args[] = { (void*)&x, (void*)&ei, (void*)&w_l, (void*)&b_l, (void*)&w_r,
                     (void*)&w_p, (void*)&b_p, (void*)&w_s, (void*)&b_s,
                     (void*)&A, (void*)&Bp, (void*)&whp, (void*)&bhc,
                     (void*)&deg, (void*)&cursor, (void*)&bsums, (void*)&elist,
                     (void*)&out };
    hipLaunchCooperativeKernel((void*)sage_all, dim3(gridsz), dim3(512),
                               args, 0, stream);
}

// Round 9
// 234.990 us; speedup vs baseline: 1.9382x; 1.9382x over previous
//
#include <hip/hip_runtime.h>
#include <hip/hip_bf16.h>
#include <math.h>

#define NN 100000
#define NE 625000
#define DIN 128
#define DH 256
#define NROWS 100096                      // 782 tiles * 128 rows
#define NTILES 782

#define SCAN_BS 1024
#define NB ((NN + SCAN_BS - 1) / SCAN_BS) // 98 scan blocks

#define HS_STRIDE 264                     // bf16 elems; 528 B rows, 16B-aligned

// prep kernel block ranges
#define XCAST_BLOCKS 12500                // NN*32 / 256 exactly
#define HIST_BLOCKS  2442
#define PACKW_BLOCKS 32
#define PACKH_BLOCKS 2
#define PREP_BLOCKS  (XCAST_BLOCKS + HIST_BLOCKS + PACKW_BLOCKS + PACKH_BLOCKS)

typedef __attribute__((ext_vector_type(8))) short bf16x8;
typedef __attribute__((ext_vector_type(4))) float f32x4;

__device__ __forceinline__ unsigned short f2bf(float f) {
    unsigned u = __builtin_bit_cast(unsigned, f);
    u += 0x7fffu + ((u >> 16) & 1u);      // RNE
    return (unsigned short)(u >> 16);
}
__device__ __forceinline__ float bflo(unsigned u) {
    return __builtin_bit_cast(float, u << 16);
}
__device__ __forceinline__ float bfhi(unsigned u) {
    return __builtin_bit_cast(float, u & 0xffff0000u);
}

// ---------------------------------------------------------------------------
// prep: fused xcast | hist | pack_w | pack_heads (independent block ranges)
// ---------------------------------------------------------------------------
__global__ __launch_bounds__(256)
void prep(const float* __restrict__ x, const int* __restrict__ ei,
          const float* __restrict__ w_l, const float* __restrict__ w_r,
          const float* __restrict__ w_p, const float* __restrict__ w_s,
          const float* __restrict__ b_p, const float* __restrict__ b_s,
          unsigned short* __restrict__ A, unsigned short* __restrict__ Bp,
          unsigned short* __restrict__ whp, float* __restrict__ bhc,
          int* __restrict__ deg) {
    const int b = blockIdx.x;
    const int t = threadIdx.x;

    if (b < XCAST_BLOCKS) {
        int idx = b * 256 + t;
        int n = idx >> 5;
        int j4 = (idx & 31) * 4;
        float4 v = *reinterpret_cast<const float4*>(x + (size_t)n * DIN + j4);
        ushort4 o = { f2bf(v.x), f2bf(v.y), f2bf(v.z), f2bf(v.w) };
        *reinterpret_cast<ushort4*>(A + (size_t)n * 256 + 128 + j4) = o;
    } else if (b < XCAST_BLOCKS + HIST_BLOCKS) {
        int e = (b - XCAST_BLOCKS) * 256 + t;
        if (e < NE) atomicAdd(&deg[ei[NE + e]], 1);
    } else if (b < XCAST_BLOCKS + HIST_BLOCKS + PACKW_BLOCKS) {
        int tid = (b - XCAST_BLOCKS - HIST_BLOCKS) * 256 + t;   // 8192
        int kt = tid >> 10;
        int ct = (tid >> 6) & 15;
        int L = tid & 63;
        int k0 = kt * 32 + (L >> 4) * 8;
        int c = ct * 16 + (L & 15);
        unsigned short v[8];
#pragma unroll
        for (int j = 0; j < 8; ++j) {
            int k = k0 + j;
            float w = (k < 128) ? w_l[k * 256 + c] : w_r[(k - 128) * 256 + c];
            v[j] = f2bf(w);
        }
        *reinterpret_cast<bf16x8*>(Bp + (size_t)tid * 8) =
            *reinterpret_cast<const bf16x8*>(v);
    } else {
        int tid = (b - XCAST_BLOCKS - HIST_BLOCKS - PACKW_BLOCKS) * 256 + t; // 512
        int kt = tid >> 6;
        int L = tid & 63;
        int k0 = kt * 32 + (L >> 4) * 8;
        int c = L & 15;
        unsigned short v[8];
#pragma unroll
        for (int j = 0; j < 8; ++j) {
            int k = k0 + j;
            float w = (c < 7) ? w_p[k * 7 + c] : (c < 13 ? w_s[k * 6 + (c - 7)] : 0.f);
            v[j] = f2bf(w);
        }
        *reinterpret_cast<bf16x8*>(whp + (size_t)tid * 8) =
            *reinterpret_cast<const bf16x8*>(v);
        if (tid < 16)
            bhc[tid] = (tid < 7) ? b_p[tid] : (tid < 13 ? b_s[tid - 7] : 0.f);
    }
}

// ---------------------------------------------------------------------------
// CSR scans
// ---------------------------------------------------------------------------
__global__ __launch_bounds__(256)
void sage_scan1(const int* __restrict__ deg, int* __restrict__ cursor,
                int* __restrict__ bsums) {
    __shared__ int ss[256];
    const int t = threadIdx.x;
    const int base = blockIdx.x * SCAN_BS + t * 4;
    int v[4];
#pragma unroll
    for (int j = 0; j < 4; ++j) v[j] = (base + j < NN) ? deg[base + j] : 0;
    int tsum = v[0] + v[1] + v[2] + v[3];
    ss[t] = tsum;
    __syncthreads();
    for (int o = 1; o < 256; o <<= 1) {
        int u = (t >= o) ? ss[t - o] : 0;
        __syncthreads();
        ss[t] += u;
        __syncthreads();
    }
    int run = ss[t] - tsum;
#pragma unroll
    for (int j = 0; j < 4; ++j) {
        if (base + j < NN) cursor[base + j] = run;
        run += v[j];
    }
    if (t == 255) bsums[blockIdx.x] = ss[255];
}

__global__ __launch_bounds__(128)
void sage_scan2(int* __restrict__ bsums) {
    __shared__ int ss[128];
    const int t = threadIdx.x;
    int v = (t < NB) ? bsums[t] : 0;
    ss[t] = v;
    __syncthreads();
    for (int o = 1; o < 128; o <<= 1) {
        int u = (t >= o) ? ss[t - o] : 0;
        __syncthreads();
        ss[t] += u;
        __syncthreads();
    }
    if (t < NB) bsums[t] = ss[t] - v;
}

// ---------------------------------------------------------------------------
// CSR fill: pos = bsums[dst>>10] + local cursor++
// ---------------------------------------------------------------------------
__global__ __launch_bounds__(256)
void sage_fill(const int* __restrict__ ei, int* __restrict__ cursor,
               const int* __restrict__ bsums, int* __restrict__ elist) {
    int e = blockIdx.x * 256 + threadIdx.x;
    if (e >= NE) return;
    int dst = ei[NE + e];
    int p = bsums[dst >> 10] + atomicAdd(&cursor[dst], 1);
    elist[p] = ei[e];
}

// ---------------------------------------------------------------------------
// Fused gather-mean + MFMA GEMM + heads + log_softmax.  (R6 structure)
// Block = 512 thr (8 waves), M-tile 128; wave owns 16 rows; 4 lanes (q) per
// row gather that row's mean dims directly in A-fragment layout.
// Gather unrolled x2: 8 independent 16B loads in flight halves the latency
// chain (the block barrier waits on its max-degree lane).
// ---------------------------------------------------------------------------
__global__ __launch_bounds__(512, 1)
void sage_gemm_fused(const unsigned short* __restrict__ A,
                     const unsigned short* __restrict__ Bp,
                     const float* __restrict__ b_l,
                     const unsigned short* __restrict__ whp,
                     const float* __restrict__ bhc,
                     const int* __restrict__ elist,
                     const int* __restrict__ cursor,
                     const int* __restrict__ bsums,
                     const int* __restrict__ deg,
                     float* __restrict__ out) {
    __shared__ __align__(16) unsigned char smem[139776];
    unsigned short* Bs = (unsigned short*)smem;          // 128 KB B frags
    unsigned short* hs = (unsigned short*)smem;          // [128][264] bf16 (alias)
    float* o13 = (float*)(smem + 131072);                // [128][17]

    const int t = threadIdx.x;
    const int wave = t >> 6;
    const int L = t & 63;
    const int q = L >> 4;
    const int m15 = L & 15;
    const int node0 = blockIdx.x * 128;
    const int n = node0 + wave * 16 + m15;   // this lane's A-frag row

    // ---- stage B (131072 B): 16 rounds x 512 thr x 16 B ----
    {
        const uint4* gsrc = reinterpret_cast<const uint4*>(Bp);
        uint4* ldst = reinterpret_cast<uint4*>(Bs);
#pragma unroll
        for (int r = 0; r < 16; ++r)
            ldst[r * 512 + t] = gsrc[r * 512 + t];
    }

    // ---- x-half A fragments (kt = 4..7): own row, direct loads ----
    bf16x8 afrag[8];
    {
        const unsigned short* arow = A + (size_t)n * 256;
#pragma unroll
        for (int kt = 4; kt < 8; ++kt)
            afrag[kt] = *reinterpret_cast<const bf16x8*>(arow + kt * 32 + q * 8);
    }

    // ---- gather-mean for kt = 0..3, unrolled x2 over neighbors ----
    {
        float macc[32];
#pragma unroll
        for (int j = 0; j < 32; ++j) macc[j] = 0.f;
        int d = 0, start = 0;
        if (n < NN) {
            d = deg[n];
            start = bsums[n >> 10] + cursor[n] - d;  // cursor = local_pfx + deg
        }
        int srcA = (d > 0) ? elist[start] : 0;
        int srcB = (d > 1) ? elist[start + 1] : 0;
        int i = 0;
        for (; i + 1 < d; i += 2) {
            const int sA = srcA, sB = srcB;
            if (i + 2 < d) srcA = elist[start + i + 2];
            if (i + 3 < d) srcB = elist[start + i + 3];
            const unsigned short* xa = A + (size_t)sA * 256 + 128 + q * 8;
            const unsigned short* xb = A + (size_t)sB * 256 + 128 + q * 8;
            const uint4 a0 = *reinterpret_cast<const uint4*>(xa);
            const uint4 a1 = *reinterpret_cast<const uint4*>(xa + 32);
            const uint4 a2 = *reinterpret_cast<const uint4*>(xa + 64);
            const uint4 a3 = *reinterpret_cast<const uint4*>(xa + 96);
            const uint4 b0 = *reinterpret_cast<const uint4*>(xb);
            const uint4 b1 = *reinterpret_cast<const uint4*>(xb + 32);
            const uint4 b2 = *reinterpret_cast<const uint4*>(xb + 64);
            const uint4 b3 = *reinterpret_cast<const uint4*>(xb + 96);
            macc[0]  += bflo(a0.x) + bflo(b0.x); macc[1]  += bfhi(a0.x) + bfhi(b0.x);
            macc[2]  += bflo(a0.y) + bflo(b0.y); macc[3]  += bfhi(a0.y) + bfhi(b0.y);
            macc[4]  += bflo(a0.z) + bflo(b0.z); macc[5]  += bfhi(a0.z) + bfhi(b0.z);
            macc[6]  += bflo(a0.w) + bflo(b0.w); macc[7]  += bfhi(a0.w) + bfhi(b0.w);
            macc[8]  += bflo(a1.x) + bflo(b1.x); macc[9]  += bfhi(a1.x) + bfhi(b1.x);
            macc[10] += bflo(a1.y) + bflo(b1.y); macc[11] += bfhi(a1.y) + bfhi(b1.y);
            macc[12] += bflo(a1.z) + bflo(b1.z); macc[13] += bfhi(a1.z) + bfhi(b1.z);
            macc[14] += bflo(a1.w) + bflo(b1.w); macc[15] += bfhi(a1.w) + bfhi(b1.w);
            macc[16] += bflo(a2.x) + bflo(b2.x); macc[17] += bfhi(a2.x) + bfhi(b2.x);
            macc[18] += bflo(a2.y) + bflo(b2.y); macc[19] += bfhi(a2.y) + bfhi(b2.y);
            macc[20] += bflo(a2.z) + bflo(b2.z); macc[21] += bfhi(a2.z) + bfhi(b2.z);
            macc[22] += bflo(a2.w) + bflo(b2.w); macc[23] += bfhi(a2.w) + bfhi(b2.w);
            macc[24] += bflo(a3.x) + bflo(b3.x); macc[25] += bfhi(a3.x) + bfhi(b3.x);
            macc[26] += bflo(a3.y) + bflo(b3.y); macc[27] += bfhi(a3.y) + bfhi(b3.y);
            macc[28] += bflo(a3.z) + bflo(b3.z); macc[29] += bfhi(a3.z) + bfhi(b3.z);
            macc[30] += bflo(a3.w) + bflo(b3.w); macc[31] += bfhi(a3.w) + bfhi(b3.w);
        }
        if (i < d) {
            const unsigned short* xa = A + (size_t)srcA * 256 + 128 + q * 8;
            const uint4 a0 = *reinterpret_cast<const uint4*>(xa);
            const uint4 a1 = *reinterpret_cast<const uint4*>(xa + 32);
            const uint4 a2 = *reinterpret_cast<const uint4*>(xa + 64);
            const uint4 a3 = *reinterpret_cast<const uint4*>(xa + 96);
            macc[0]  += bflo(a0.x); macc[1]  += bfhi(a0.x);
            macc[2]  += bflo(a0.y); macc[3]  += bfhi(a0.y);
            macc[4]  += bflo(a0.z); macc[5]  += bfhi(a0.z);
            macc[6]  += bflo(a0.w); macc[7]  += bfhi(a0.w);
            macc[8]  += bflo(a1.x); macc[9]  += bfhi(a1.x);
            macc[10] += bflo(a1.y); macc[11] += bfhi(a1.y);
            macc[12] += bflo(a1.z); macc[13] += bfhi(a1.z);
            macc[14] += bflo(a1.w); macc[15] += bfhi(a1.w);
            macc[16] += bflo(a2.x); macc[17] += bfhi(a2.x);
            macc[18] += bflo(a2.y); macc[19] += bfhi(a2.y);
            macc[20] += bflo(a2.z); macc[21] += bfhi(a2.z);
            macc[22] += bflo(a2.w); macc[23] += bfhi(a2.w);
            macc[24] += bflo(a3.x); macc[25] += bfhi(a3.x);
            macc[26] += bflo(a3.y); macc[27] += bfhi(a3.y);
            macc[28] += bflo(a3.z); macc[29] += bfhi(a3.z);
            macc[30] += bflo(a3.w); macc[31] += bfhi(a3.w);
        }
        const float invd = (d > 0) ? 1.f / (float)d : 0.f;
#pragma unroll
        for (int kt = 0; kt < 4; ++kt) {
            unsigned short vv[8];
#pragma unroll
            for (int j = 0; j < 8; ++j) vv[j] = f2bf(macc[kt * 8 + j] * invd);
            afrag[kt] = *reinterpret_cast<const bf16x8*>(vv);
        }
    }

    f32x4 acc[16];
#pragma unroll
    for (int ct = 0; ct < 16; ++ct) acc[ct] = (f32x4){0.f, 0.f, 0.f, 0.f};

    __syncthreads();   // B staged (gather is register-private)

#pragma unroll
    for (int kt = 0; kt < 8; ++kt) {
#pragma unroll
        for (int ct = 0; ct < 16; ++ct) {
            bf16x8 b = *reinterpret_cast<const bf16x8*>(
                Bs + ((size_t)(kt * 16 + ct) * 64 + L) * 8);
            acc[ct] = __builtin_amdgcn_mfma_f32_16x16x32_bf16(afrag[kt], b, acc[ct], 0, 0, 0);
        }
    }

    __syncthreads();   // all waves done reading Bs; reuse as hs

    // ---- epilogue: bias + relu -> hs bf16 (stride 264) ----
#pragma unroll
    for (int ct = 0; ct < 16; ++ct) {
        const int c = ct * 16 + m15;
        const float blv = b_l[c];
        const int r0 = wave * 16 + q * 4;
#pragma unroll
        for (int r = 0; r < 4; ++r)
            hs[(r0 + r) * HS_STRIDE + c] = f2bf(fmaxf(acc[ct][r] + blv, 0.f));
    }
    __syncthreads();

    // ---- heads via MFMA: wave's 16 rows x 16 (13 used) cols, K=256 ----
    {
        f32x4 acch = (f32x4){0.f, 0.f, 0.f, 0.f};
        const unsigned short* hrow = hs + (size_t)(wave * 16 + m15) * HS_STRIDE;
#pragma unroll
        for (int kt = 0; kt < 8; ++kt) {
            bf16x8 ah = *reinterpret_cast<const bf16x8*>(hrow + kt * 32 + q * 8);
            bf16x8 bh = *reinterpret_cast<const bf16x8*>(whp + ((size_t)(kt * 64 + L)) * 8);
            acch = __builtin_amdgcn_mfma_f32_16x16x32_bf16(ah, bh, acch, 0, 0, 0);
        }
        if (m15 < 13) {
            const float bh = bhc[m15];
#pragma unroll
            for (int r = 0; r < 4; ++r)
                o13[(wave * 16 + q * 4 + r) * 17 + m15] = acch[r] + bh;
        }
    }
    __syncthreads();

    // ---- log_softmax + write ----
    if (t < 128) {
        const int gnode = node0 + t;
        if (gnode < NN) {
            float v[7], mx = -1e30f;
#pragma unroll
            for (int j = 0; j < 7; ++j) { v[j] = o13[t * 17 + j]; mx = fmaxf(mx, v[j]); }
            float sum = 0.f;
#pragma unroll
            for (int j = 0; j < 7; ++j) sum += expf(v[j] - mx);
            const float lse = mx + logf(sum);
#pragma unroll
            for (int j = 0; j < 7; ++j) out[(size_t)gnode * 7 + j] = v[j] - lse;

            float u[6], mx2 = -1e30f;
#pragma unroll
            for (int j = 0; j < 6; ++j) { u[j] = o13[t * 17 + 7 + j]; mx2 = fmaxf(mx2, u[j]); }
            float sum2 = 0.f;
#pragma unroll
            for (int j = 0; j < 6; ++j) sum2 += expf(u[j] - mx2);
            const float lse2 = mx2 + logf(sum2);
#pragma unroll
            for (int j = 0; j < 6; ++j) out[(size_t)NN * 7 + (size_t)gnode * 6 + j] = u[j] - lse2;
        }
    }
}

extern "C" void kernel_launch(void* const* d_in, const int* in_sizes, int n_in,
                              void* d_out, int out_size, void* d_ws, size_t ws_size,
                              hipStream_t stream) {
    const float* x   = (const float*)d_in[0];
    const int*   ei  = (const int*)d_in[1];
    const float* w_l = (const float*)d_in[2];
    const float* b_l = (const float*)d_in[3];
    const float* w_r = (const float*)d_in[4];
    const float* w_p = (const float*)d_in[5];
    const float* b_p = (const float*)d_in[6];
    const float* w_s = (const float*)d_in[7];
    const float* b_s = (const float*)d_in[8];
    float* out = (float*)d_out;

    // workspace layout (~54.7 MB)
    unsigned short* A   = (unsigned short*)d_ws;     // [NROWS][256] bf16: [mean|x]
    unsigned short* Bp  = A + (size_t)NROWS * 256;   // 65536 bf16 MFMA layout
    unsigned short* whp = Bp + 65536;                // 4096 bf16 head B-frags
    float* bhc  = (float*)(whp + 4096);              // [16] head biases
    int* deg    = (int*)(bhc + 16);                  // NN
    int* cursor = deg + NN;                          // NN (local prefix)
    int* bsums  = cursor + NN;                       // 128
    int* elist  = bsums + 128;                       // NE

    hipMemsetAsync(deg, 0, NN * sizeof(int), stream);

    prep<<<PREP_BLOCKS, 256, 0, stream>>>(x, ei, w_l, w_r, w_p, w_s, b_p, b_s,
                                          A, Bp, whp, bhc, deg);
    sage_scan1<<<NB, 256, 0, stream>>>(deg, cursor, bsums);
    sage_scan2<<<1, 128, 0, stream>>>(bsums);
    sage_fill<<<(NE + 255) / 256, 256, 0, stream>>>(ei, cursor, bsums, elist);

    sage_gemm_fused<<<NTILES, 512, 0, stream>>>(A, Bp, b_l, whp, bhc,
                                                elist, cursor, bsums, deg, out);
}